// Round 8
// baseline (21324.982 us; speedup 1.0000x reference)
//
#include <hip/hip_runtime.h>
#include <math.h>

typedef float f32x4 __attribute__((ext_vector_type(4)));

__device__ __forceinline__ float sigm(float x) { return 1.f / (1.f + expf(-x)); }

// ---------------- h0 = c0 = mean_p A[n][k][p] ----------------
__global__ void k_init(const float* __restrict__ Af, float* __restrict__ h32,
                       float* __restrict__ cst) {
  int idx = blockIdx.x * 256 + threadIdx.x;   // n*512 + k, 131072 total
  const float* ap = Af + (size_t)idx * 16;
  float s = 0.f;
#pragma unroll
  for (int p = 0; p < 16; ++p) s += ap[p];
  s *= 0.0625f;
  h32[idx] = s;   // time-buffer 0
  cst[idx] = s;
}

// ---------------- per-step kernel 1: scores -> softmax -> attn ----------------
// One block per batch row n; thread tid owns k = tid. All fp32.
__global__ __launch_bounds__(512) void k_phaseA(const float* __restrict__ Af,
                                                const float* __restrict__ h32,
                                                float* __restrict__ attn32, int t) {
  __shared__ float SC[8192];    // [512 k][16 p]
  __shared__ float ared[512];   // [32 seg][16 p]
  __shared__ float wlds[16];
  const int tid = threadIdx.x;
  const int n = blockIdx.x;

  float Areg[16];
  const f32x4* A4 = (const f32x4*)(Af + (size_t)n * 8192 + tid * 16);
#pragma unroll
  for (int q4 = 0; q4 < 4; ++q4) {
    f32x4 v = A4[q4];
#pragma unroll
    for (int e = 0; e < 4; ++e) Areg[q4 * 4 + e] = v[e];
  }
  float hk = h32[(size_t)(t & 1) * 131072 + (size_t)n * 512 + tid];
#pragma unroll
  for (int p = 0; p < 16; ++p) SC[tid * 16 + p] = hk * Areg[p];
  __syncthreads();
  {
    int seg = tid >> 4, pp = tid & 15;
    float s = 0.f;
#pragma unroll
    for (int q = 0; q < 16; ++q) s += SC[(seg * 16 + q) * 16 + pp];
    ared[seg * 16 + pp] = s;
  }
  __syncthreads();
  if (tid < 16) {
    float s = 0.f;
#pragma unroll
    for (int q = 0; q < 32; ++q) s += ared[q * 16 + tid];
    s *= 0.04419417382415922f;   // 1/sqrt(512)
    float m = s;
#pragma unroll
    for (int o = 8; o >= 1; o >>= 1) m = fmaxf(m, __shfl_xor(m, o, 16));
    float e = __expf(s - m);
    float se = e;
#pragma unroll
    for (int o = 8; o >= 1; o >>= 1) se += __shfl_xor(se, o, 16);
    wlds[tid] = e / se;
  }
  __syncthreads();
  float av = 0.f;
#pragma unroll
  for (int p = 0; p < 16; ++p) av += Areg[p] * wlds[p];
  attn32[(size_t)n * 512 + tid] = av;
}

// ---------------- per-step kernel 2: naive fp32 GEMM + cell ----------------
// 512 blocks x 256 threads. Block (g = bid>>6, j = bid&63): rows n0=g*32..+31,
// cols j*8..j*8+7 (x4 gates). Thread (rT = tid&31, cT = tid>>5) owns output
// (row n0+rT, col j*8+cT) for all 4 gates -> LSTM cell fully thread-local.
// Weights read DIRECTLY from the input buffers: W*[k*2048 + gate*512 + col].
__global__ __launch_bounds__(256) void k_cell(
    const float* __restrict__ bv, const float* __restrict__ x,
    const float* __restrict__ Wx, const float* __restrict__ Wh,
    const float* __restrict__ Wat,
    float* __restrict__ h32, const float* __restrict__ attn32,
    float* __restrict__ cst, float* __restrict__ out, int t) {
  __shared__ float Atile[32][129];   // +1 pad: conflict-free column reads

  const int tid = threadIdx.x;
  const int bid = blockIdx.x;
  const int g = bid >> 6, j = bid & 63;
  const int n0 = g * 32;
  const int rT = tid & 31, cT = tid >> 5;
  const int jcol = j * 8 + cT;
  const int rb = t & 1, wb = rb ^ 1;
  const float* hR = h32 + (size_t)rb * 131072;

  float acc0 = 0.f, acc1 = 0.f, acc2 = 0.f, acc3 = 0.f;

  for (int tile = 0; tile < 12; ++tile) {
    // stage A-panel tile: 32 rows x 128 k  (tiles 0-3: x_t, 4-7: h, 8-11: attn)
    {
      const int row = tid >> 3;   // 0..31
      const int kq = tid & 7;     // 8 threads per row
#pragma unroll
      for (int rep = 0; rep < 4; ++rep) {
        int kf = (kq * 4 + rep) * 4;        // 0,4,...,124
        int kglob = tile * 128 + kf;
        const float* src;
        if (tile < 4)
          src = x + ((size_t)(n0 + row) * 128 + t) * 512 + kglob;
        else if (tile < 8)
          src = hR + (size_t)(n0 + row) * 512 + (kglob - 512);
        else
          src = attn32 + (size_t)(n0 + row) * 512 + (kglob - 1024);
        float4 v = *(const float4*)src;
        Atile[row][kf + 0] = v.x;
        Atile[row][kf + 1] = v.y;
        Atile[row][kf + 2] = v.z;
        Atile[row][kf + 3] = v.w;
      }
    }
    __syncthreads();
    const float* W0 = (tile < 4) ? (Wx + (size_t)tile * 128 * 2048)
                    : (tile < 8) ? (Wh + (size_t)(tile - 4) * 128 * 2048)
                                 : (Wat + (size_t)(tile - 8) * 128 * 2048);
#pragma unroll 4
    for (int kk = 0; kk < 128; ++kk) {
      float av = Atile[rT][kk];
      const float* Wr = W0 + (size_t)kk * 2048 + jcol;
      acc0 += av * Wr[0];
      acc1 += av * Wr[512];
      acc2 += av * Wr[1024];
      acc3 += av * Wr[1536];
    }
    __syncthreads();
  }

  // gates + state update (fp32)
  float ai = acc0 + bv[jcol];
  float af_ = acc1 + bv[512 + jcol];
  float ao = acc2 + bv[1024 + jcol];
  float ag = acc3 + bv[1536 + jcol];
  float ig = sigm(ai), fg = sigm(af_), og = sigm(ao), gg = tanhf(ag);
  const size_t cix = (size_t)(n0 + rT) * 512 + jcol;
  float c = cst[cix];
  float cn = fg * c + ig * gg;
  cst[cix] = cn;
  float hn = og * tanhf(cn);
  h32[(size_t)wb * 131072 + cix] = hn;
  out[((size_t)(n0 + rT) * 128 + t) * 512 + jcol] = hn;   // fp32 output
}

// ---------------- Host launcher ----------------

extern "C" void kernel_launch(void* const* d_in, const int* in_sizes, int n_in,
                              void* d_out, int out_size, void* d_ws, size_t ws_size,
                              hipStream_t stream) {
  (void)in_sizes; (void)n_in; (void)out_size; (void)ws_size;
  const float* x   = (const float*)d_in[0];   // (256,128,512)
  const float* Af  = (const float*)d_in[1];   // (256,512,16)
  const float* Wx  = (const float*)d_in[2];   // (512,2048)
  const float* Wh  = (const float*)d_in[3];   // (512,2048)
  const float* Wat = (const float*)d_in[4];   // (512,2048)
  const float* bv  = (const float*)d_in[5];   // (2048,)
  float* out = (float*)d_out;                 // fp32 output (reference dtype)

  char* ws = (char*)d_ws;
  size_t off = 0;
  auto alloc = [&](size_t nb) {
    char* p = ws + off; off = (off + nb + 255) & ~(size_t)255; return p;
  };
  float* h32    = (float*)alloc(262144ull * 4);   // 2 time-buffers
  float* attn32 = (float*)alloc(131072ull * 4);
  float* cst    = (float*)alloc(131072ull * 4);

  k_init<<<512, 256, 0, stream>>>(Af, h32, cst);
  for (int t = 0; t < 128; ++t) {
    k_phaseA<<<256, 512, 0, stream>>>(Af, h32, attn32, t);
    k_cell<<<512, 256, 0, stream>>>(bv, x, Wx, Wh, Wat, h32, attn32, cst, out, t);
  }
}

// Round 11
// 5178.469 us; speedup vs baseline: 4.1180x; 4.1180x over previous
//
#include <hip/hip_runtime.h>
#include <math.h>

typedef unsigned short u16;
typedef _Float16 h16;
typedef _Float16 f16x8 __attribute__((ext_vector_type(8)));
typedef float f32x4 __attribute__((ext_vector_type(4)));

__device__ __forceinline__ float sigm(float x) { return 1.f / (1.f + expf(-x)); }

// ---------------- Prologue kernels ----------------

// Pack W = [Wx;Wh;Wattn] (1536 x 2048 f32) into per-colblock f16 hi/lo MFMA
// b-frag streams. Layout: [j 0..64)[ks 0..48)[cf 0..2)[l 0..64)[e 0..8)
// element = W[k = ks*32 + (l>>4)*8 + e][acol], acol = (c32>>3)*512 + j*8 + (c32&7),
// c32 = cf*16 + (l&15).  lo scaled by 2^12 (exact) to stay in fp16 normal range.
__global__ void k_pack_w(const float* __restrict__ Wx, const float* __restrict__ Wh,
                         const float* __restrict__ Wat,
                         h16* __restrict__ WhiS, h16* __restrict__ WloS) {
  unsigned idx = blockIdx.x * 256 + threadIdx.x;   // 0..3145727
  unsigned e = idx & 7, l = (idx >> 3) & 63, cf = (idx >> 9) & 1;
  unsigned t2 = idx >> 10;
  unsigned j = t2 / 48u, ks = t2 - j * 48u;
  unsigned k = ks * 32 + ((l >> 4) << 3) + e;
  unsigned c32 = cf * 16 + (l & 15);
  unsigned acol = (c32 >> 3) * 512 + j * 8 + (c32 & 7);
  float v = (k < 512) ? Wx[(size_t)k * 2048 + acol]
          : (k < 1024) ? Wh[(size_t)(k - 512) * 2048 + acol]
                       : Wat[(size_t)(k - 1024) * 2048 + acol];
  h16 hi = (h16)v;
  WhiS[idx] = hi;
  WloS[idx] = (h16)((v - (float)hi) * 4096.f);
}

// x (f32) -> xhi/xlo fp16 streams, same [n][t][k] layout
__global__ void k_xsplit(const float* __restrict__ x, h16* __restrict__ xhi,
                         h16* __restrict__ xlo) {
  size_t i = ((size_t)blockIdx.x * 256 + threadIdx.x) * 4;
  float4 v = *(const float4*)(x + i);
  union { h16 h[4]; uint2 u; } a, b;
  float vv[4] = {v.x, v.y, v.z, v.w};
#pragma unroll
  for (int e = 0; e < 4; ++e) {
    h16 hh = (h16)vv[e];
    a.h[e] = hh;
    b.h[e] = (h16)((vv[e] - (float)hh) * 4096.f);
  }
  *(uint2*)(xhi + i) = a.u;
  *(uint2*)(xlo + i) = b.u;
}

// h0 = c0 = mean_p A[n][k][p] (fp32) + fp16 hi/lo split; zero barrier words
__global__ void k_init(const float* __restrict__ Af, float* __restrict__ h32,
                       h16* __restrict__ hhi, h16* __restrict__ hlo,
                       float* __restrict__ cst, int* __restrict__ bar) {
  int idx = blockIdx.x * 256 + threadIdx.x;   // n*512 + k, 131072 total
  const float* ap = Af + (size_t)idx * 16;
  float s = 0.f;
#pragma unroll
  for (int p = 0; p < 16; ++p) s += ap[p];
  s *= 0.0625f;
  h32[idx] = s;   // time-buffer 0
  cst[idx] = s;
  h16 hh = (h16)s;
  hhi[idx] = hh;
  hlo[idx] = (h16)((s - (float)hh) * 4096.f);
  if (idx < 256) bar[idx] = 0;   // re-zeroed every launch (graph replay safe)
}

// ---------------- Main persistent kernel ----------------
// 256 blocks x 512 threads, 1 block/CU (134 KB LDS). Block (g = bid>>6, j = bid&63):
// rows n0..n0+63 (n0 = g*64), h-cols j*8..j*8+7 (x4 gates = 32 a-cols).
// Monotonic-epoch hierarchical grid barrier: 8 leaf counters + root cnt + root gen;
// bounded spin watchdog degrades pathology to wrong-but-terminating.
// Protocol empirically validated (R4 matched the naive fp32 anchor bit-for-bit
// through the out-dtype artifact).

template<bool XPRE>
__global__ __launch_bounds__(512, 2) void rnn_main(
    const float* __restrict__ Af, const float* __restrict__ bv,
    const float* __restrict__ x, const h16* __restrict__ xhi, const h16* __restrict__ xlo,
    const h16* __restrict__ WhiS, const h16* __restrict__ WloS,
    float* __restrict__ h32, h16* __restrict__ hhi, h16* __restrict__ hlo,
    h16* __restrict__ ahiB, h16* __restrict__ aloB,
    float* __restrict__ cst, float* __restrict__ out, int* __restrict__ bar) {
  __shared__ f16x8 Wlds[6144];    // [ks 48][cf 2][l 64] b-frags of Whi : 98304 B
  __shared__ float P[4 * 2112];   // 4 slots of [64 rows][33] : 33792 B (also phase-A scratch)
  __shared__ float ared[512];     // [32][16]
  __shared__ float wlds[16];

  const int tid = threadIdx.x;
  const int l = tid & 63, wv = tid >> 6;
  const int bid = blockIdx.x;
  const int g = bid >> 6, j = bid & 63;
  const int n0 = g * 64;
  const int myn = n0 + j;              // phase-A row owned by this block
  const int rA = n0 + (l & 15);        // A-frag row base
  const int klane = (l >> 4) * 8;

  // Whi slice -> LDS (persistent across all 128 steps)
  {
    const uint4* src = (const uint4*)(WhiS + (size_t)j * 49152);
    uint4* dst = (uint4*)Wlds;
    for (int i = tid; i < 6144; i += 512) dst[i] = src[i];
  }
  const h16* wloJ = WloS + (size_t)j * 49152;

  // cell-phase constants: thread -> (row rC, col qC)
  const int rC = tid >> 3, qC = tid & 7;
  const int colC = j * 8 + qC;
  const float b_i = bv[colC], b_f = bv[512 + colC], b_o = bv[1024 + colC],
              b_g = bv[1536 + colC];

  int ep = 0;
  __syncthreads();

  for (int t = 0; t < 128; ++t) {
    const int rb = t & 1, wb = rb ^ 1;
    const float* h32r = h32 + (size_t)rb * 131072;
    const h16* hhiR = hhi + (size_t)rb * 131072;
    const h16* hloR = hlo + (size_t)rb * 131072;

    // ---------- PHASE A: scores -> softmax -> attn (row myn), all fp32 ----------
    float Areg[16];
    {
      const f32x4* A4 = (const f32x4*)(Af + (size_t)myn * 8192 + tid * 16);
#pragma unroll
      for (int q4 = 0; q4 < 4; ++q4) {
        f32x4 v = A4[q4];
#pragma unroll
        for (int e = 0; e < 4; ++e) Areg[q4 * 4 + e] = v[e];
      }
      float hk = h32r[(size_t)myn * 512 + tid];   // thread owns k = tid
      float* SC = P;                              // [512][16] scratch
#pragma unroll
      for (int p = 0; p < 16; ++p) SC[tid * 16 + p] = hk * Areg[p];
    }
    __syncthreads();
    {
      int seg = tid >> 4, pp = tid & 15;
      float s = 0.f;
#pragma unroll
      for (int q = 0; q < 16; ++q) s += P[(seg * 16 + q) * 16 + pp];
      ared[seg * 16 + pp] = s;
    }
    __syncthreads();
    if (tid < 16) {
      float s = 0.f;
#pragma unroll
      for (int q = 0; q < 32; ++q) s += ared[q * 16 + tid];
      s *= 0.04419417382415922f;   // 1/sqrt(512)
      float m = s;
#pragma unroll
      for (int o = 8; o >= 1; o >>= 1) m = fmaxf(m, __shfl_xor(m, o, 16));
      float e = __expf(s - m);
      float se = e;
#pragma unroll
      for (int o = 8; o >= 1; o >>= 1) se += __shfl_xor(se, o, 16);
      wlds[tid] = e / se;
    }
    __syncthreads();
    {
      float av = 0.f;
#pragma unroll
      for (int p = 0; p < 16; ++p) av += Areg[p] * wlds[p];
      h16 ah = (h16)av;
      ahiB[(size_t)myn * 512 + tid] = ah;
      aloB[(size_t)myn * 512 + tid] = (h16)((av - (float)ah) * 4096.f);
    }
    // ---- arrive bar1 (split-phase; wait happens after x/h GEMM part) ----
    ++ep;
    __syncthreads();   // drains this block's attn stores before the arrive
    if (tid == 0) {
      __threadfence();
      int old = __hip_atomic_fetch_add(bar + (bid & 7) * 16, 1, __ATOMIC_RELAXED,
                                       __HIP_MEMORY_SCOPE_AGENT);
      if ((old & 31) == 31) {
        int o2 = __hip_atomic_fetch_add(bar + 128, 1, __ATOMIC_RELAXED,
                                        __HIP_MEMORY_SCOPE_AGENT);
        if ((o2 & 7) == 7)
          __hip_atomic_fetch_add(bar + 160, 1, __ATOMIC_RELAXED,
                                 __HIP_MEMORY_SCOPE_AGENT);
      }
    }

    // ---------- GEMM: a = [x|h|attn] @ [Wx;Wh;Wattn], fp16 hi/lo 3-pass ----------
    f32x4 acc1[4][2], acc2[4][2];
#pragma unroll
    for (int rt = 0; rt < 4; ++rt)
#pragma unroll
      for (int cf = 0; cf < 2; ++cf) {
        acc1[rt][cf] = (f32x4){0.f, 0.f, 0.f, 0.f};
        acc2[rt][cf] = (f32x4){0.f, 0.f, 0.f, 0.f};
      }

    auto kstep = [&](int ksg) {
      const f16x8 bh0 = Wlds[(ksg * 2 + 0) * 64 + l];
      const f16x8 bh1 = Wlds[(ksg * 2 + 1) * 64 + l];
      const f16x8 bl0 = *(const f16x8*)(wloJ + ((size_t)(ksg * 2 + 0) * 64 + l) * 8);
      const f16x8 bl1 = *(const f16x8*)(wloJ + ((size_t)(ksg * 2 + 1) * 64 + l) * 8);
      f16x8 Ah[4], Al[4];
      const int kg = ksg * 32;
      if (kg < 512) {
        const size_t base = ((size_t)rA * 128 + t) * 512 + kg + klane;
        if (XPRE) {
#pragma unroll
          for (int rt = 0; rt < 4; ++rt) {
            Ah[rt] = *(const f16x8*)(xhi + base + (size_t)rt * 1048576);
            Al[rt] = *(const f16x8*)(xlo + base + (size_t)rt * 1048576);
          }
        } else {
#pragma unroll
          for (int rt = 0; rt < 4; ++rt) {
            const float* xp = x + base + (size_t)rt * 1048576;
            f32x4 v0 = *(const f32x4*)xp, v1 = *(const f32x4*)(xp + 4);
            float vv[8] = {v0[0], v0[1], v0[2], v0[3], v1[0], v1[1], v1[2], v1[3]};
#pragma unroll
            for (int e = 0; e < 8; ++e) {
              h16 hh = (h16)vv[e];
              Ah[rt][e] = hh;
              Al[rt][e] = (h16)((vv[e] - (float)hh) * 4096.f);
            }
          }
        }
      } else if (kg < 1024) {
        const size_t base = (size_t)rA * 512 + (kg - 512) + klane;
#pragma unroll
        for (int rt = 0; rt < 4; ++rt) {
          Ah[rt] = *(const f16x8*)(hhiR + base + rt * 8192);
          Al[rt] = *(const f16x8*)(hloR + base + rt * 8192);
        }
      } else {
        const size_t base = (size_t)rA * 512 + (kg - 1024) + klane;
#pragma unroll
        for (int rt = 0; rt < 4; ++rt) {
          Ah[rt] = *(const f16x8*)(ahiB + base + rt * 8192);
          Al[rt] = *(const f16x8*)(aloB + base + rt * 8192);
        }
      }
#pragma unroll
      for (int rt = 0; rt < 4; ++rt) {
        acc1[rt][0] = __builtin_amdgcn_mfma_f32_16x16x32_f16(Ah[rt], bh0, acc1[rt][0], 0, 0, 0);
        acc1[rt][1] = __builtin_amdgcn_mfma_f32_16x16x32_f16(Ah[rt], bh1, acc1[rt][1], 0, 0, 0);
        acc2[rt][0] = __builtin_amdgcn_mfma_f32_16x16x32_f16(Al[rt], bh0, acc2[rt][0], 0, 0, 0);
        acc2[rt][1] = __builtin_amdgcn_mfma_f32_16x16x32_f16(Al[rt], bh1, acc2[rt][1], 0, 0, 0);
        acc2[rt][0] = __builtin_amdgcn_mfma_f32_16x16x32_f16(Ah[rt], bl0, acc2[rt][0], 0, 0, 0);
        acc2[rt][1] = __builtin_amdgcn_mfma_f32_16x16x32_f16(Ah[rt], bl1, acc2[rt][1], 0, 0, 0);
      }
    };

    // part 1: ksg = wv + 8i, i=0..3  (kg < 1024: x and h — independent of bar1)
#pragma unroll
    for (int i = 0; i < 4; ++i) kstep(wv + 8 * i);

    // ---- wait bar1 ----
    if (tid == 0) {
      int spins = 0;
      while (__hip_atomic_load(bar + 160, __ATOMIC_RELAXED, __HIP_MEMORY_SCOPE_AGENT) < ep) {
        __builtin_amdgcn_s_sleep(2);
        if (++spins > (1 << 17)) break;   // watchdog (~13ms): never wedge the GPU
      }
      (void)__hip_atomic_load(bar + 160, __ATOMIC_ACQUIRE, __HIP_MEMORY_SCOPE_AGENT);
    }
    __syncthreads();

    // part 2: attn k-range (i = 4,5)
#pragma unroll
    for (int i = 4; i < 6; ++i) kstep(wv + 8 * i);

    // combine hi + 2^-12 * lo-cross
    float accf[4][2][4];
#pragma unroll
    for (int rt = 0; rt < 4; ++rt)
#pragma unroll
      for (int cf = 0; cf < 2; ++cf)
#pragma unroll
        for (int rg = 0; rg < 4; ++rg)
          accf[rt][cf][rg] = acc1[rt][cf][rg] + acc2[rt][cf][rg] * (1.f / 4096.f);

    auto publish = [&](int slot) {
#pragma unroll
      for (int rt = 0; rt < 4; ++rt)
#pragma unroll
        for (int cf = 0; cf < 2; ++cf)
#pragma unroll
          for (int rg = 0; rg < 4; ++rg)
            P[slot * 2112 + (rt * 16 + (l >> 4) * 4 + rg) * 33 + cf * 16 + (l & 15)] =
                accf[rt][cf][rg];
    };
    auto addin = [&](int slot) {
#pragma unroll
      for (int rt = 0; rt < 4; ++rt)
#pragma unroll
        for (int cf = 0; cf < 2; ++cf)
#pragma unroll
          for (int rg = 0; rg < 4; ++rg)
            accf[rt][cf][rg] +=
                P[slot * 2112 + (rt * 16 + (l >> 4) * 4 + rg) * 33 + cf * 16 + (l & 15)];
    };

    if (wv >= 4) publish(wv - 4);
    __syncthreads();
    if (wv < 4) addin(wv);
    if (wv == 2) publish(2);
    if (wv == 3) publish(3);
    __syncthreads();
    if (wv == 0) addin(2);
    if (wv == 1) { addin(3); publish(1); }
    __syncthreads();
    if (wv == 0) { addin(1); publish(0); }
    __syncthreads();

    // ---------- CELL: gates (fp32) + state update, all 512 threads ----------
    {
      float ai = P[rC * 33 + qC] + b_i;
      float af_ = P[rC * 33 + 8 + qC] + b_f;
      float ao = P[rC * 33 + 16 + qC] + b_o;
      float ag = P[rC * 33 + 24 + qC] + b_g;
      float ig = sigm(ai), fg = sigm(af_), og = sigm(ao), gg = tanhf(ag);
      const size_t cix = (size_t)(n0 + rC) * 512 + colC;
      float c = cst[cix];
      float cn = fg * c + ig * gg;
      cst[cix] = cn;
      float hn = og * tanhf(cn);
      h32[(size_t)wb * 131072 + cix] = hn;
      h16 hh = (h16)hn;
      hhi[(size_t)wb * 131072 + cix] = hh;
      hlo[(size_t)wb * 131072 + cix] = (h16)((hn - (float)hh) * 4096.f);
      out[((size_t)(n0 + rC) * 128 + t) * 512 + colC] = hn;   // fp32 output
    }
    // ---- bar2 ----
    ++ep;
    __syncthreads();
    if (tid == 0) {
      __threadfence();
      int old = __hip_atomic_fetch_add(bar + (bid & 7) * 16, 1, __ATOMIC_RELAXED,
                                       __HIP_MEMORY_SCOPE_AGENT);
      if ((old & 31) == 31) {
        int o2 = __hip_atomic_fetch_add(bar + 128, 1, __ATOMIC_RELAXED,
                                        __HIP_MEMORY_SCOPE_AGENT);
        if ((o2 & 7) == 7)
          __hip_atomic_fetch_add(bar + 160, 1, __ATOMIC_RELAXED,
                                 __HIP_MEMORY_SCOPE_AGENT);
      }
      int spins = 0;
      while (__hip_atomic_load(bar + 160, __ATOMIC_RELAXED, __HIP_MEMORY_SCOPE_AGENT) < ep) {
        __builtin_amdgcn_s_sleep(2);
        if (++spins > (1 << 17)) break;
      }
      (void)__hip_atomic_load(bar + 160, __ATOMIC_ACQUIRE, __HIP_MEMORY_SCOPE_AGENT);
    }
    __syncthreads();
  }
}

// ---------------- Host launcher ----------------

extern "C" void kernel_launch(void* const* d_in, const int* in_sizes, int n_in,
                              void* d_out, int out_size, void* d_ws, size_t ws_size,
                              hipStream_t stream) {
  (void)in_sizes; (void)n_in; (void)out_size;
  const float* x   = (const float*)d_in[0];   // (256,128,512)
  const float* Af  = (const float*)d_in[1];   // (256,512,16)
  const float* Wx  = (const float*)d_in[2];   // (512,2048)
  const float* Wh  = (const float*)d_in[3];   // (512,2048)
  const float* Wat = (const float*)d_in[4];   // (512,2048)
  const float* bv  = (const float*)d_in[5];   // (2048,)
  float* out = (float*)d_out;                 // fp32 output (reference dtype)

  char* ws = (char*)d_ws;
  size_t off = 0;
  auto alloc = [&](size_t nb) {
    char* p = ws + off; off = (off + nb + 255) & ~(size_t)255; return p;
  };
  int*   bar  = (int*)alloc(1024);
  h16*   WhiS = (h16*)alloc(3145728ull * 2);
  h16*   WloS = (h16*)alloc(3145728ull * 2);
  float* h32  = (float*)alloc(262144ull * 4);
  h16*   hhi  = (h16*)alloc(262144ull * 2);
  h16*   hlo  = (h16*)alloc(262144ull * 2);
  h16*   ahiB = (h16*)alloc(131072ull * 2);
  h16*   aloB = (h16*)alloc(131072ull * 2);
  float* cst  = (float*)alloc(131072ull * 4);
  size_t base_end = off;
  h16* xhi = (h16*)alloc(16777216ull * 2);
  h16* xlo = (h16*)alloc(16777216ull * 2);
  bool xpre = (ws_size >= base_end + 2ull * 16777216ull * 2 + 4096);

  k_pack_w<<<12288, 256, 0, stream>>>(Wx, Wh, Wat, WhiS, WloS);
  k_init<<<512, 256, 0, stream>>>(Af, h32, hhi, hlo, cst, bar);

  if (xpre) {
    k_xsplit<<<16384, 256, 0, stream>>>(x, xhi, xlo);
    void* args[] = { (void*)&Af, (void*)&bv, (void*)&x, (void*)&xhi, (void*)&xlo,
                     (void*)&WhiS, (void*)&WloS, (void*)&h32, (void*)&hhi, (void*)&hlo,
                     (void*)&ahiB, (void*)&aloB, (void*)&cst, (void*)&out, (void*)&bar };
    hipError_t err = hipLaunchCooperativeKernel((void*)rnn_main<true>, dim3(256),
                                                dim3(512), args, 0, stream);
    if (err != hipSuccess) {
      (void)hipGetLastError();
      rnn_main<true><<<256, 512, 0, stream>>>(Af, bv, x, xhi, xlo, WhiS, WloS,
                                              h32, hhi, hlo, ahiB, aloB, cst, out, bar);
    }
  } else {
    void* args[] = { (void*)&Af, (void*)&bv, (void*)&x, (void*)&xhi, (void*)&xlo,
                     (void*)&WhiS, (void*)&WloS, (void*)&h32, (void*)&hhi, (void*)&hlo,
                     (void*)&ahiB, (void*)&aloB, (void*)&cst, (void*)&out, (void*)&bar };
    hipError_t err = hipLaunchCooperativeKernel((void*)rnn_main<false>, dim3(256),
                                                dim3(512), args, 0, stream);
    if (err != hipSuccess) {
      (void)hipGetLastError();
      rnn_main<false><<<256, 512, 0, stream>>>(Af, bv, x, xhi, xlo, WhiS, WloS,
                                               h32, hhi, hlo, ahiB, aloB, cst, out, bar);
    }
  }
}